// Round 11
// baseline (102.008 us; speedup 1.0000x reference)
//
#include <hip/hip_runtime.h>

// LIF multi-step: spikes[t] = Heaviside(h[t] - 1.0), h[t] = 0.5*v + 0.25 + x[t],
// v' = s ? 0.5 : h.  T=64, B=32, N=32768. Memory-bound streaming scan.
//
// R10: revert to R8 (measured best of the 97-102us plateau, 97.4us).
// Final structure: f4/thread (1KiB/wave loads), plain loads (L2/L3 absorb
// ~50% of read fetch across replays), nt stores (write-only stream, no
// allocate), 16-deep batched loop body, 3/4-cacheable partition (neutral but
// was the best-measured config), 1024 blocks x 256 = 16 waves/CU.
// Plateau evidence: R4 101.8 / R6 100.6 / R7 98.0 / R8 97.4 / R9 100.1 —
// logical 537MB/97.4us = 5.51 TB/s = 88% of the same-mix copy ceiling.

#define T_STEPS 64
#define BATCH 16

typedef float f4 __attribute__((ext_vector_type(4)));

template <bool NT_LOAD>
__device__ __forceinline__ void lif_run(const f4* __restrict__ xp,
                                        f4* __restrict__ op, int bn4) {
    f4 v = {0.5f, 0.5f, 0.5f, 0.5f};

    #pragma unroll
    for (int c = 0; c < T_STEPS / BATCH; ++c) {
        f4 xt[BATCH];
        #pragma unroll
        for (int i = 0; i < BATCH; ++i) {
            if (NT_LOAD)
                xt[i] = __builtin_nontemporal_load(xp + (size_t)i * bn4);
            else
                xt[i] = xp[(size_t)i * bn4];
        }

        #pragma unroll
        for (int i = 0; i < BATCH; ++i) {
            float hx = fmaf(0.5f, v.x, 0.25f + xt[i].x);
            float hy = fmaf(0.5f, v.y, 0.25f + xt[i].y);
            float hz = fmaf(0.5f, v.z, 0.25f + xt[i].z);
            float hw = fmaf(0.5f, v.w, 0.25f + xt[i].w);

            f4 s;
            s.x = (hx >= 1.0f) ? 1.0f : 0.0f;
            s.y = (hy >= 1.0f) ? 1.0f : 0.0f;
            s.z = (hz >= 1.0f) ? 1.0f : 0.0f;
            s.w = (hw >= 1.0f) ? 1.0f : 0.0f;

            v.x = (hx >= 1.0f) ? 0.5f : hx;
            v.y = (hy >= 1.0f) ? 0.5f : hy;
            v.z = (hz >= 1.0f) ? 0.5f : hz;
            v.w = (hw >= 1.0f) ? 0.5f : hw;

            __builtin_nontemporal_store(s, op + (size_t)i * bn4);
        }

        xp += (size_t)BATCH * bn4;
        op += (size_t)BATCH * bn4;
    }
}

__global__ __launch_bounds__(256, 4) void lif_kernel(const f4* __restrict__ x,
                                                     f4* __restrict__ out,
                                                     int bn4, int cache_cut) {
    int idx = blockIdx.x * blockDim.x + threadIdx.x;
    if (idx >= bn4) return;

    if (idx < cache_cut)
        lif_run<false>(x + idx, out + idx, bn4);  // cacheable region
    else
        lif_run<true>(x + idx, out + idx, bn4);   // streaming (nt) region
}

extern "C" void kernel_launch(void* const* d_in, const int* in_sizes, int n_in,
                              void* d_out, int out_size, void* d_ws, size_t ws_size,
                              hipStream_t stream) {
    const f4* x = (const f4*)d_in[0];
    f4* out = (f4*)d_out;

    int total = in_sizes[0];
    int bn = total / T_STEPS;
    int bn4 = bn / 4;

    int cache_cut = (bn4 / 4) * 3;  // 3/4 of columns -> cacheable

    int block = 256;
    int grid = (bn4 + block - 1) / block;
    lif_kernel<<<grid, block, 0, stream>>>(x, out, bn4, cache_cut);
}